// Round 9
// baseline (255.615 us; speedup 1.0000x reference)
//
#include <hip/hip_runtime.h>
#include <hip/hip_bf16.h>

typedef __bf16 v8bf __attribute__((ext_vector_type(8)));
typedef unsigned short v8us __attribute__((ext_vector_type(8)));
typedef float v4f __attribute__((ext_vector_type(4)));

#define B_ 2
#define T_ 2048
#define D_ 1024
#define H_ 16
#define HD_ 64
#define M_ 4096   // B*T
#define LDST 88   // fallback GEMM LDS row stride (bf16 elems)
#define PSTR 72   // attn P^T LDS row stride
#define LOG2E 1.44269504f

static __device__ __forceinline__ unsigned short f2bfbits(float f) {
    __hip_bfloat16 h = __float2bfloat16(f);
    unsigned short u;
    __builtin_memcpy(&u, &h, 2);
    return u;
}

static __device__ __forceinline__ v8us load8_f32_to_bf16(const float* g) {
    float4 fa = *(const float4*)g;
    float4 fb = *(const float4*)(g + 4);
    v8us p;
    p[0] = f2bfbits(fa.x); p[1] = f2bfbits(fa.y);
    p[2] = f2bfbits(fa.z); p[3] = f2bfbits(fa.w);
    p[4] = f2bfbits(fb.x); p[5] = f2bfbits(fb.y);
    p[6] = f2bfbits(fb.z); p[7] = f2bfbits(fb.w);
    return p;
}

// async 16B global -> LDS (direct DMA, no VGPR round-trip)
static __device__ __forceinline__ void async16(const void* g, void* l) {
    __builtin_amdgcn_global_load_lds(
        (const __attribute__((address_space(1))) void*)g,
        (__attribute__((address_space(3))) void*)l, 16, 0, 0);
}

// one dispatch converting hs (2048 blocks) + 4 weights (512 blocks each)
__global__ __launch_bounds__(256) void cvt_multi(
    const float* __restrict__ hs, const float* __restrict__ wq,
    const float* __restrict__ wk, const float* __restrict__ wv,
    const float* __restrict__ wo, __hip_bfloat16* __restrict__ hsb,
    __hip_bfloat16* __restrict__ wqb, __hip_bfloat16* __restrict__ wkb,
    __hip_bfloat16* __restrict__ wvb, __hip_bfloat16* __restrict__ wob) {
    int bid = blockIdx.x;
    const float* src;
    __hip_bfloat16* dst;
    int off;
    if (bid < 2048) {
        src = hs; dst = hsb; off = bid;
    } else {
        int w = (bid - 2048) >> 9;
        off = (bid - 2048) & 511;
        src = (w == 0) ? wq : (w == 1) ? wk : (w == 2) ? wv : wo;
        dst = (w == 0) ? wqb : (w == 1) ? wkb : (w == 2) ? wvb : wob;
    }
    int i = (off * 256 + threadIdx.x) * 8;
    *(v8us*)&dst[i] = load8_f32_to_bf16(&src[i]);
}

// ------------- fused QKV GEMM: 128x128 tile, BK=64, N=3072 -------------
// W = [Wq;Wk;Wv] bf16 [3072,1024]; mid = n0>>10 selects epilogue:
// 0=Q (scale 0.125*log2e, [B,H,T,HD]), 1=K ([B,H,T,HD]), 2=V^T ([B,H,HD,T]).
__global__ __launch_bounds__(256) void gemm_qkv(
    const __hip_bfloat16* __restrict__ A, const __hip_bfloat16* __restrict__ W,
    const float* __restrict__ bq_, const float* __restrict__ bk_,
    const float* __restrict__ bv_, __hip_bfloat16* __restrict__ qo,
    __hip_bfloat16* __restrict__ ko, __hip_bfloat16* __restrict__ vo) {
    __shared__ __hip_bfloat16 sA[128 * 64];
    __shared__ __hip_bfloat16 sW[128 * 64];
    const int tid = threadIdx.x;
    const int wid = tid >> 6, lane = tid & 63;
    const int quad = lane >> 4, lq = lane & 15;
    const int wm = wid & 1, wn = wid >> 1;
    const int n0 = blockIdx.x * 128, m0 = blockIdx.y * 128;
    const int mid = n0 >> 10;
    const float* bias = (mid == 0) ? bq_ : (mid == 1) ? bk_ : bv_;

    v4f acc[4][4] = {};

    for (int k0 = 0; k0 < 1024; k0 += 64) {
        __syncthreads();
        for (int it = 0; it < 8; ++it) {
            int Lc = it * 256 + tid;
            int l1 = Lc & 1023;
            int row = l1 >> 3, pos = l1 & 7;
            if (it < 4)
                async16(&A[(size_t)(m0 + row) * 1024 + k0 + ((pos ^ (row & 7)) * 8)],
                        &sA[l1 * 8]);
            else
                async16(&W[(size_t)(n0 + row) * 1024 + k0 + ((pos ^ (row & 7)) * 8)],
                        &sW[l1 * 8]);
        }
        __syncthreads();
        for (int c = 0; c < 2; ++c) {
            v8bf af[4], wf[4];
            for (int mf = 0; mf < 4; ++mf) {
                int row = wm * 64 + mf * 16 + lq;
                af[mf] = *(const v8bf*)&sA[row * 64 + (((c * 4 + quad) ^ (lq & 7)) * 8)];
            }
            for (int nf = 0; nf < 4; ++nf) {
                int row = wn * 64 + nf * 16 + lq;
                wf[nf] = *(const v8bf*)&sW[row * 64 + (((c * 4 + quad) ^ (lq & 7)) * 8)];
            }
            for (int mf = 0; mf < 4; ++mf)
                for (int nf = 0; nf < 4; ++nf)
                    acc[mf][nf] = __builtin_amdgcn_mfma_f32_16x16x32_bf16(
                        af[mf], wf[nf], acc[mf][nf], 0, 0, 0);
        }
    }

    for (int nf = 0; nf < 4; ++nf) {
        int n = n0 + wn * 64 + nf * 16 + lq;
        int nl = n & 1023;
        int hh = nl >> 6, dd = nl & 63;
        float bvv = bias[nl];
        for (int mf = 0; mf < 4; ++mf) {
            int mbase = m0 + wm * 64 + mf * 16 + quad * 4;
            int bb = mbase >> 11;
            if (mid == 2) {
                int t0 = mbase & 2047;
                ushort4 pk;
                pk.x = f2bfbits(acc[mf][nf][0] + bvv);
                pk.y = f2bfbits(acc[mf][nf][1] + bvv);
                pk.z = f2bfbits(acc[mf][nf][2] + bvv);
                pk.w = f2bfbits(acc[mf][nf][3] + bvv);
                *(ushort4*)&vo[(((size_t)(bb * H_ + hh)) * HD_ + dd) * T_ + t0] = pk;
            } else {
                __hip_bfloat16* dst = (mid == 0) ? qo : ko;
                float sc = (mid == 0) ? 0.125f * LOG2E : 1.0f;
                for (int r = 0; r < 4; ++r) {
                    int m = mbase + r;
                    int t = m & 2047;
                    dst[(((size_t)(bb * H_ + hh)) * T_ + t) * HD_ + dd] =
                        __float2bfloat16((acc[mf][nf][r] + bvv) * sc);
                }
            }
        }
    }
}

// ------------- out-proj GEMM: bf16 A/W, tile 128Mx64N, BK=64 -------------
__global__ __launch_bounds__(256) void gemm_out(
    const __hip_bfloat16* __restrict__ A, const __hip_bfloat16* __restrict__ W,
    const float* __restrict__ bias, float* __restrict__ out) {
    __shared__ __hip_bfloat16 sA[128 * 64];
    __shared__ __hip_bfloat16 sW[64 * 64];
    const int tid = threadIdx.x;
    const int wid = tid >> 6, lane = tid & 63;
    const int quad = lane >> 4, lq = lane & 15;
    const int wm = wid & 1, wn = wid >> 1;
    const int n0 = blockIdx.x * 64, m0 = blockIdx.y * 128;

    v4f acc[4][2] = {};

    for (int k0 = 0; k0 < 1024; k0 += 64) {
        __syncthreads();
        for (int it = 0; it < 4; ++it) {
            int Lc = wid * 256 + it * 64 + lane;
            int row = Lc >> 3, pos = Lc & 7;
            async16(&A[(size_t)(m0 + row) * 1024 + k0 + ((pos ^ (row & 7)) * 8)],
                    &sA[Lc * 8]);
        }
        for (int it = 0; it < 2; ++it) {
            int Lc = wid * 128 + it * 64 + lane;
            int row = Lc >> 3, pos = Lc & 7;
            async16(&W[(size_t)(n0 + row) * 1024 + k0 + ((pos ^ (row & 7)) * 8)],
                    &sW[Lc * 8]);
        }
        __syncthreads();
        for (int c = 0; c < 2; ++c) {
            v8bf af[4], wf[2];
            for (int mf = 0; mf < 4; ++mf) {
                int row = wm * 64 + mf * 16 + lq;
                af[mf] = *(const v8bf*)&sA[row * 64 + (((c * 4 + quad) ^ (lq & 7)) * 8)];
            }
            for (int nf = 0; nf < 2; ++nf) {
                int row = wn * 32 + nf * 16 + lq;
                wf[nf] = *(const v8bf*)&sW[row * 64 + (((c * 4 + quad) ^ (lq & 7)) * 8)];
            }
            for (int mf = 0; mf < 4; ++mf)
                for (int nf = 0; nf < 2; ++nf)
                    acc[mf][nf] = __builtin_amdgcn_mfma_f32_16x16x32_bf16(
                        af[mf], wf[nf], acc[mf][nf], 0, 0, 0);
        }
    }
    for (int nf = 0; nf < 2; ++nf) {
        int n = n0 + wn * 32 + nf * 16 + lq;
        float bv = bias[n];
        for (int mf = 0; mf < 4; ++mf) {
            int mbase = m0 + wm * 64 + mf * 16 + quad * 4;
            for (int r = 0; r < 4; ++r)
                out[(size_t)(mbase + r) * 1024 + n] = acc[mf][nf][r] + bv;
        }
    }
}

// ---------------- fallback GEMM (fp32 inputs, padded LDS) ----------------
template <int EPI, bool ABF16, bool WBF16>
__global__ __launch_bounds__(256) void gemm128(
    const void* __restrict__ Av, const void* __restrict__ Wv_,
    const float* __restrict__ bias, void* __restrict__ outv) {
    __shared__ __hip_bfloat16 sA[128 * LDST];
    __shared__ __hip_bfloat16 sW[128 * LDST];
    const int tid = threadIdx.x;
    const int wid = tid >> 6, lane = tid & 63;
    const int quad = lane >> 4, lq = lane & 15;
    const int wm = wid & 1, wn = wid >> 1;
    const int n0 = blockIdx.x * 128, m0 = blockIdx.y * 128;
    v4f acc[4][4] = {};
    for (int k0 = 0; k0 < 1024; k0 += 64) {
        __syncthreads();
        for (int i = 0; i < 4; ++i) {
            int f = i * 256 + tid;
            int row = f >> 3, ch = f & 7;
            if constexpr (ABF16) {
                const __hip_bfloat16* A = (const __hip_bfloat16*)Av;
                *(int4*)&sA[row * LDST + ch * 8] =
                    *(const int4*)&A[(size_t)(m0 + row) * 1024 + k0 + ch * 8];
            } else {
                const float* A = (const float*)Av;
                *(v8us*)&sA[row * LDST + ch * 8] =
                    load8_f32_to_bf16(&A[(size_t)(m0 + row) * 1024 + k0 + ch * 8]);
            }
            if constexpr (WBF16) {
                const __hip_bfloat16* W = (const __hip_bfloat16*)Wv_;
                *(int4*)&sW[row * LDST + ch * 8] =
                    *(const int4*)&W[(size_t)(n0 + row) * 1024 + k0 + ch * 8];
            } else {
                const float* W = (const float*)Wv_;
                *(v8us*)&sW[row * LDST + ch * 8] =
                    load8_f32_to_bf16(&W[(size_t)(n0 + row) * 1024 + k0 + ch * 8]);
            }
        }
        __syncthreads();
        for (int c = 0; c < 2; ++c) {
            v8bf af[4], wf[4];
            for (int mf = 0; mf < 4; ++mf)
                af[mf] = *(const v8bf*)&sA[(wm * 64 + mf * 16 + lq) * LDST + c * 32 + quad * 8];
            for (int nf = 0; nf < 4; ++nf)
                wf[nf] = *(const v8bf*)&sW[(wn * 64 + nf * 16 + lq) * LDST + c * 32 + quad * 8];
            for (int mf = 0; mf < 4; ++mf)
                for (int nf = 0; nf < 4; ++nf)
                    acc[mf][nf] = __builtin_amdgcn_mfma_f32_16x16x32_bf16(
                        af[mf], wf[nf], acc[mf][nf], 0, 0, 0);
        }
    }
    for (int nf = 0; nf < 4; ++nf) {
        int n = n0 + wn * 64 + nf * 16 + lq;
        float bv = bias[n];
        for (int mf = 0; mf < 4; ++mf) {
            int mbase = m0 + wm * 64 + mf * 16 + quad * 4;
            if constexpr (EPI == 2) {
                __hip_bfloat16* out = (__hip_bfloat16*)outv;
                int bb = mbase >> 11, t0 = mbase & 2047;
                int hh = n >> 6, dd = n & 63;
                ushort4 pk;
                pk.x = f2bfbits(acc[mf][nf][0] + bv);
                pk.y = f2bfbits(acc[mf][nf][1] + bv);
                pk.z = f2bfbits(acc[mf][nf][2] + bv);
                pk.w = f2bfbits(acc[mf][nf][3] + bv);
                *(ushort4*)&out[(((size_t)(bb * H_ + hh)) * HD_ + dd) * T_ + t0] = pk;
            } else {
                for (int r = 0; r < 4; ++r) {
                    int m = mbase + r;
                    float v = acc[mf][nf][r] + bv;
                    if constexpr (EPI == 0) {
                        __hip_bfloat16* out = (__hip_bfloat16*)outv;
                        v *= 0.125f * LOG2E;
                        int bb = m >> 11, t = m & 2047, hh = n >> 6, dd = n & 63;
                        out[(((size_t)(bb * H_ + hh)) * T_ + t) * HD_ + dd] = __float2bfloat16(v);
                    } else if constexpr (EPI == 1) {
                        __hip_bfloat16* out = (__hip_bfloat16*)outv;
                        int bb = m >> 11, t = m & 2047, hh = n >> 6, dd = n & 63;
                        out[(((size_t)(bb * H_ + hh)) * T_ + t) * HD_ + dd] = __float2bfloat16(v);
                    } else {
                        float* out = (float*)outv;
                        out[(size_t)m * 1024 + n] = v;
                    }
                }
            }
        }
    }
}

// -------- flash attention: 512 thr, 8 waves x 16 q, full ping-pong -------
// grid (T/128, B*H). S^T = K Q^T in exp2 domain (q carries 0.125*log2e).
// K/V double-buffered AND mask register-pipelined one iteration ahead,
// with mask loads issued AFTER the staging loads: no vmem wait exists
// inside the compute phase (vmcnt FIFO stays untouched until the single
// end-of-iteration barrier, whose vmcnt(0) drains loads issued a full
// compute phase earlier).
__global__ __launch_bounds__(512) void attn_kernel(
    const __hip_bfloat16* __restrict__ q, const __hip_bfloat16* __restrict__ k,
    const __hip_bfloat16* __restrict__ vt, const float* __restrict__ mask,
    __hip_bfloat16* __restrict__ out) {
    __shared__ __hip_bfloat16 sK[2][64 * 64];    // [key][d], swizzled
    __shared__ __hip_bfloat16 sV[2][64 * 64];    // [d][key], swizzled
    __shared__ __hip_bfloat16 pT[8][16 * PSTR];  // per-wave P^T [q][64key]
    const int tid = threadIdx.x;
    const int wid = tid >> 6, lane = tid & 63;
    const int quad = lane >> 4, lq = lane & 15;
    const int bh = blockIdx.y;
    const int b = bh >> 4, h = bh & 15;
    const int qt = blockIdx.x * 128 + wid * 16 + lq;  // this lane's q row

    v8bf bq[2];
    for (int c = 0; c < 2; ++c)
        bq[c] = *(const v8bf*)&q[((size_t)bh * T_ + qt) * HD_ + c * 32 + quad * 8];

    const float* mrow = mask + ((size_t)b * T_ + qt) * T_;
    const __hip_bfloat16* kbase = k + (size_t)bh * T_ * HD_;
    const __hip_bfloat16* vbase = vt + (size_t)bh * HD_ * T_;

    // staging coords: thread -> one sK chunk and one sV chunk (512 each)
    const int srow = tid >> 3, spos = tid & 7;
    const int sswz = (spos ^ (srow & 7)) * 8;

    float l = 0.f;
    v4f o[4] = {};
    float4 mcur[4], mnxt[4];

    // prologue: stage tile 0, then mask 0
    async16(&kbase[(size_t)srow * HD_ + sswz], &sK[0][tid * 8]);
    async16(&vbase[(size_t)srow * T_ + sswz], &sV[0][tid * 8]);
    for (int ki = 0; ki < 4; ++ki)
        mcur[ki] = *(const float4*)&mrow[ki * 16 + quad * 4];
    __syncthreads();  // drains prologue staging + mask

    for (int itn = 0; itn < T_ / 64; ++itn) {
        const int kt0 = itn * 64, buf = itn & 1;
        // issue next tile's staging FIRST, then next mask (FIFO order matters)
        if (itn + 1 < T_ / 64) {
            const int kn = kt0 + 64;
            async16(&kbase[(size_t)(kn + srow) * HD_ + sswz], &sK[buf ^ 1][tid * 8]);
            async16(&vbase[(size_t)srow * T_ + kn + sswz], &sV[buf ^ 1][tid * 8]);
            for (int ki = 0; ki < 4; ++ki)
                mnxt[ki] = *(const float4*)&mrow[kn + ki * 16 + quad * 4];
        }

        // ---- compute on buf / mcur: no vmem waits in here ----
        v4f st[4] = {};
        for (int ki = 0; ki < 4; ++ki)
            for (int c = 0; c < 2; ++c) {
                int row = ki * 16 + lq;
                v8bf ka = *(const v8bf*)&sK[buf][row * 64 + (((c * 4 + quad) ^ (lq & 7)) * 8)];
                st[ki] = __builtin_amdgcn_mfma_f32_16x16x32_bf16(ka, bq[c], st[ki], 0, 0, 0);
            }
        for (int ki = 0; ki < 4; ++ki)
            for (int r = 0; r < 4; ++r) {
                st[ki][r] = __builtin_amdgcn_exp2f(fmaf((&mcur[ki].x)[r], LOG2E, st[ki][r]));
                l += st[ki][r];
            }
        for (int ki = 0; ki < 4; ++ki) {
            ushort4 pk;
            pk.x = f2bfbits(st[ki][0]); pk.y = f2bfbits(st[ki][1]);
            pk.z = f2bfbits(st[ki][2]); pk.w = f2bfbits(st[ki][3]);
            *(ushort4*)&pT[wid][lq * PSTR + ki * 16 + quad * 4] = pk;
        }
        for (int c = 0; c < 2; ++c) {
            v8bf pb = *(const v8bf*)&pT[wid][lq * PSTR + c * 32 + quad * 8];
            for (int nt = 0; nt < 4; ++nt) {
                int row = nt * 16 + lq;
                v8bf va = *(const v8bf*)&sV[buf][row * 64 + (((c * 4 + quad) ^ (lq & 7)) * 8)];
                o[nt] = __builtin_amdgcn_mfma_f32_16x16x32_bf16(va, pb, o[nt], 0, 0, 0);
            }
        }
        // rotate mask regs (waitcnt lands here, right before the barrier)
        for (int ki = 0; ki < 4; ++ki) mcur[ki] = mnxt[ki];
        // single barrier: (a) next staging+mask drained (issued a full
        // compute phase ago); (b) all waves done reading buf -> safe to
        // overwrite it in the NEXT iteration.
        __syncthreads();
    }

    l += __shfl_xor(l, 16);
    l += __shfl_xor(l, 32);
    float inv = 1.0f / l;
    for (int nt = 0; nt < 4; ++nt) {
        ushort4 pk;
        pk.x = f2bfbits(o[nt][0] * inv); pk.y = f2bfbits(o[nt][1] * inv);
        pk.z = f2bfbits(o[nt][2] * inv); pk.w = f2bfbits(o[nt][3] * inv);
        *(ushort4*)&out[((size_t)b * T_ + qt) * D_ + h * HD_ + nt * 16 + quad * 4] = pk;
    }
}

extern "C" void kernel_launch(void* const* d_in, const int* in_sizes, int n_in,
                              void* d_out, int out_size, void* d_ws, size_t ws_size,
                              hipStream_t stream) {
    const float* hs   = (const float*)d_in[0];
    const float* mask = (const float*)d_in[1];
    const float* Wq   = (const float*)d_in[2];
    const float* bq   = (const float*)d_in[3];
    const float* Wk   = (const float*)d_in[4];
    const float* bk   = (const float*)d_in[5];
    const float* Wv   = (const float*)d_in[6];
    const float* bv   = (const float*)d_in[7];
    const float* Wo   = (const float*)d_in[8];
    const float* bo   = (const float*)d_in[9];
    float* out = (float*)d_out;

    const size_t TEN = (size_t)B_ * H_ * T_ * HD_;  // 4,194,304
    const size_t WEL = (size_t)D_ * D_;             // 1,048,576
    __hip_bfloat16* q_ws  = (__hip_bfloat16*)d_ws;
    __hip_bfloat16* k_ws  = q_ws + TEN;
    __hip_bfloat16* vt_ws = k_ws + TEN;
    __hip_bfloat16* at_ws = vt_ws + TEN;

    dim3 qkvgrid(3072 / 128, M_ / 128);  // (24, 32) = 768 blocks -> 3/CU
    dim3 outgrid(D_ / 64, M_ / 128);     // (16, 32) = 512 blocks
    dim3 ogrid(D_ / 128, M_ / 128);      // fallback grid
    dim3 agrid(T_ / 128, B_ * H_);       // (16, 32) = 512 blocks of 512 thr

    const size_t need = (4 * TEN + TEN + 4 * WEL) * sizeof(__hip_bfloat16);
    if (ws_size >= need) {
        __hip_bfloat16* hsb = at_ws + TEN;
        __hip_bfloat16* wqb = hsb + TEN;   // wqb/wkb/wvb contiguous = [3072,1024]
        __hip_bfloat16* wkb = wqb + WEL;
        __hip_bfloat16* wvb = wkb + WEL;
        __hip_bfloat16* wob = wvb + WEL;
        cvt_multi<<<2048 + 4 * 512, 256, 0, stream>>>(hs, Wq, Wk, Wv, Wo,
                                                      hsb, wqb, wkb, wvb, wob);
        gemm_qkv<<<qkvgrid, 256, 0, stream>>>(hsb, wqb, bq, bk, bv, q_ws, k_ws, vt_ws);
        attn_kernel<<<agrid, 512, 0, stream>>>(q_ws, k_ws, vt_ws, mask, at_ws);
        gemm_out<<<outgrid, 256, 0, stream>>>(at_ws, wob, bo, out);
    } else {
        gemm128<0, false, false><<<ogrid, 256, 0, stream>>>(hs, Wq, bq, q_ws);
        gemm128<1, false, false><<<ogrid, 256, 0, stream>>>(hs, Wk, bk, k_ws);
        gemm128<2, false, false><<<ogrid, 256, 0, stream>>>(hs, Wv, bv, vt_ws);
        attn_kernel<<<agrid, 512, 0, stream>>>(q_ws, k_ws, vt_ws, mask, at_ws);
        gemm128<3, true, false><<<ogrid, 256, 0, stream>>>(at_ws, Wo, bo, out);
    }
}

// Round 10
// 240.276 us; speedup vs baseline: 1.0638x; 1.0638x over previous
//
#include <hip/hip_runtime.h>
#include <hip/hip_bf16.h>

typedef __bf16 v8bf __attribute__((ext_vector_type(8)));
typedef unsigned short v8us __attribute__((ext_vector_type(8)));
typedef float v4f __attribute__((ext_vector_type(4)));

#define B_ 2
#define T_ 2048
#define D_ 1024
#define H_ 16
#define HD_ 64
#define M_ 4096   // B*T
#define LDST 88   // fallback GEMM LDS row stride (bf16 elems)
#define PSTR 72   // attn P^T LDS row stride
#define LOG2E 1.44269504f

static __device__ __forceinline__ unsigned short f2bfbits(float f) {
    __hip_bfloat16 h = __float2bfloat16(f);
    unsigned short u;
    __builtin_memcpy(&u, &h, 2);
    return u;
}

static __device__ __forceinline__ v8us load8_f32_to_bf16(const float* g) {
    float4 fa = *(const float4*)g;
    float4 fb = *(const float4*)(g + 4);
    v8us p;
    p[0] = f2bfbits(fa.x); p[1] = f2bfbits(fa.y);
    p[2] = f2bfbits(fa.z); p[3] = f2bfbits(fa.w);
    p[4] = f2bfbits(fb.x); p[5] = f2bfbits(fb.y);
    p[6] = f2bfbits(fb.z); p[7] = f2bfbits(fb.w);
    return p;
}

// async 16B global -> LDS (direct DMA, no VGPR round-trip)
static __device__ __forceinline__ void async16(const void* g, void* l) {
    __builtin_amdgcn_global_load_lds(
        (const __attribute__((address_space(1))) void*)g,
        (__attribute__((address_space(3))) void*)l, 16, 0, 0);
}

// one dispatch converting hs (2048 blocks) + 4 weights (512 blocks each)
__global__ __launch_bounds__(256) void cvt_multi(
    const float* __restrict__ hs, const float* __restrict__ wq,
    const float* __restrict__ wk, const float* __restrict__ wv,
    const float* __restrict__ wo, __hip_bfloat16* __restrict__ hsb,
    __hip_bfloat16* __restrict__ wqb, __hip_bfloat16* __restrict__ wkb,
    __hip_bfloat16* __restrict__ wvb, __hip_bfloat16* __restrict__ wob) {
    int bid = blockIdx.x;
    const float* src;
    __hip_bfloat16* dst;
    int off;
    if (bid < 2048) {
        src = hs; dst = hsb; off = bid;
    } else {
        int w = (bid - 2048) >> 9;
        off = (bid - 2048) & 511;
        src = (w == 0) ? wq : (w == 1) ? wk : (w == 2) ? wv : wo;
        dst = (w == 0) ? wqb : (w == 1) ? wkb : (w == 2) ? wvb : wob;
    }
    int i = (off * 256 + threadIdx.x) * 8;
    *(v8us*)&dst[i] = load8_f32_to_bf16(&src[i]);
}

// ------------- fused QKV GEMM: 128x128 tile, BK=64, N=3072 -------------
// W = [Wq;Wk;Wv] bf16 [3072,1024]; mid = n0>>10 selects epilogue:
// 0=Q (scale 0.125*log2e, [B,H,T,HD]), 1=K ([B,H,T,HD]), 2=V^T ([B,H,HD,T]).
// mids 0/1 run the MFMA operand-SWAPPED (C^T): C row-dim = feature n, so
// the 4 r-values pack into one ushort4 along dd (no scalar scatter).
__global__ __launch_bounds__(256) void gemm_qkv(
    const __hip_bfloat16* __restrict__ A, const __hip_bfloat16* __restrict__ W,
    const float* __restrict__ bq_, const float* __restrict__ bk_,
    const float* __restrict__ bv_, __hip_bfloat16* __restrict__ qo,
    __hip_bfloat16* __restrict__ ko, __hip_bfloat16* __restrict__ vo) {
    __shared__ __hip_bfloat16 sA[128 * 64];
    __shared__ __hip_bfloat16 sW[128 * 64];
    const int tid = threadIdx.x;
    const int wid = tid >> 6, lane = tid & 63;
    const int quad = lane >> 4, lq = lane & 15;
    const int wm = wid & 1, wn = wid >> 1;
    const int n0 = blockIdx.x * 128, m0 = blockIdx.y * 128;
    const int mid = n0 >> 10;
    const float* bias = (mid == 0) ? bq_ : (mid == 1) ? bk_ : bv_;

    v4f acc[4][4] = {};

    for (int k0 = 0; k0 < 1024; k0 += 64) {
        __syncthreads();
        for (int it = 0; it < 8; ++it) {
            int Lc = it * 256 + tid;
            int l1 = Lc & 1023;
            int row = l1 >> 3, pos = l1 & 7;
            if (it < 4)
                async16(&A[(size_t)(m0 + row) * 1024 + k0 + ((pos ^ (row & 7)) * 8)],
                        &sA[l1 * 8]);
            else
                async16(&W[(size_t)(n0 + row) * 1024 + k0 + ((pos ^ (row & 7)) * 8)],
                        &sW[l1 * 8]);
        }
        __syncthreads();
        for (int c = 0; c < 2; ++c) {
            v8bf af[4], wf[4];
            for (int mf = 0; mf < 4; ++mf) {
                int row = wm * 64 + mf * 16 + lq;
                af[mf] = *(const v8bf*)&sA[row * 64 + (((c * 4 + quad) ^ (lq & 7)) * 8)];
            }
            for (int nf = 0; nf < 4; ++nf) {
                int row = wn * 64 + nf * 16 + lq;
                wf[nf] = *(const v8bf*)&sW[row * 64 + (((c * 4 + quad) ^ (lq & 7)) * 8)];
            }
            if (mid == 2) {
                for (int mf = 0; mf < 4; ++mf)
                    for (int nf = 0; nf < 4; ++nf)
                        acc[mf][nf] = __builtin_amdgcn_mfma_f32_16x16x32_bf16(
                            af[mf], wf[nf], acc[mf][nf], 0, 0, 0);
            } else {
                // swapped: A-op = W rows (n), B-op = hs rows (m)
                for (int i = 0; i < 4; ++i)
                    for (int j = 0; j < 4; ++j)
                        acc[i][j] = __builtin_amdgcn_mfma_f32_16x16x32_bf16(
                            wf[i], af[j], acc[i][j], 0, 0, 0);
            }
        }
    }

    if (mid == 2) {
        // C layout: row = m(token) = quad*4+r, col = n = lq -> pack along t
        for (int nf = 0; nf < 4; ++nf) {
            int n = n0 + wn * 64 + nf * 16 + lq;
            int nl = n & 1023;
            int hh = nl >> 6, dd = nl & 63;
            float bvv = bias[nl];
            for (int mf = 0; mf < 4; ++mf) {
                int mbase = m0 + wm * 64 + mf * 16 + quad * 4;
                int bb = mbase >> 11, t0 = mbase & 2047;
                ushort4 pk;
                pk.x = f2bfbits(acc[mf][nf][0] + bvv);
                pk.y = f2bfbits(acc[mf][nf][1] + bvv);
                pk.z = f2bfbits(acc[mf][nf][2] + bvv);
                pk.w = f2bfbits(acc[mf][nf][3] + bvv);
                *(ushort4*)&vo[(((size_t)(bb * H_ + hh)) * HD_ + dd) * T_ + t0] = pk;
            }
        }
    } else {
        // swapped C^T layout: row = n(feature) = quad*4+r, col = m = lq
        __hip_bfloat16* dst = (mid == 0) ? qo : ko;
        const float sc = (mid == 0) ? 0.125f * LOG2E : 1.0f;
        for (int i = 0; i < 4; ++i) {
            int nb = n0 + wn * 64 + i * 16 + quad * 4;  // 4 consecutive n
            int nl = nb & 1023;
            int hh = nl >> 6, dd = nl & 63;
            float4 bv4 = *(const float4*)&bias[nl];
            for (int j = 0; j < 4; ++j) {
                int m = m0 + wm * 64 + j * 16 + lq;
                int bb = m >> 11, t = m & 2047;
                ushort4 pk;
                pk.x = f2bfbits((acc[i][j][0] + bv4.x) * sc);
                pk.y = f2bfbits((acc[i][j][1] + bv4.y) * sc);
                pk.z = f2bfbits((acc[i][j][2] + bv4.z) * sc);
                pk.w = f2bfbits((acc[i][j][3] + bv4.w) * sc);
                *(ushort4*)&dst[(((size_t)(bb * H_ + hh)) * T_ + t) * HD_ + dd] = pk;
            }
        }
    }
}

// ------- out-proj GEMM: swapped operands -> packed float4 stores --------
__global__ __launch_bounds__(256) void gemm_out(
    const __hip_bfloat16* __restrict__ A, const __hip_bfloat16* __restrict__ W,
    const float* __restrict__ bias, float* __restrict__ out) {
    __shared__ __hip_bfloat16 sA[128 * 64];
    __shared__ __hip_bfloat16 sW[64 * 64];
    const int tid = threadIdx.x;
    const int wid = tid >> 6, lane = tid & 63;
    const int quad = lane >> 4, lq = lane & 15;
    const int wm = wid & 1, wn = wid >> 1;
    const int n0 = blockIdx.x * 64, m0 = blockIdx.y * 128;

    v4f acc[2][4] = {};

    for (int k0 = 0; k0 < 1024; k0 += 64) {
        __syncthreads();
        for (int it = 0; it < 4; ++it) {
            int Lc = wid * 256 + it * 64 + lane;
            int row = Lc >> 3, pos = Lc & 7;
            async16(&A[(size_t)(m0 + row) * 1024 + k0 + ((pos ^ (row & 7)) * 8)],
                    &sA[Lc * 8]);
        }
        for (int it = 0; it < 2; ++it) {
            int Lc = wid * 128 + it * 64 + lane;
            int row = Lc >> 3, pos = Lc & 7;
            async16(&W[(size_t)(n0 + row) * 1024 + k0 + ((pos ^ (row & 7)) * 8)],
                    &sW[Lc * 8]);
        }
        __syncthreads();
        for (int c = 0; c < 2; ++c) {
            v8bf af[4], wf[2];
            for (int mf = 0; mf < 4; ++mf) {
                int row = wm * 64 + mf * 16 + lq;
                af[mf] = *(const v8bf*)&sA[row * 64 + (((c * 4 + quad) ^ (lq & 7)) * 8)];
            }
            for (int nf = 0; nf < 2; ++nf) {
                int row = wn * 32 + nf * 16 + lq;
                wf[nf] = *(const v8bf*)&sW[row * 64 + (((c * 4 + quad) ^ (lq & 7)) * 8)];
            }
            for (int i = 0; i < 2; ++i)
                for (int j = 0; j < 4; ++j)
                    acc[i][j] = __builtin_amdgcn_mfma_f32_16x16x32_bf16(
                        wf[i], af[j], acc[i][j], 0, 0, 0);
        }
    }
    // swapped C^T: row = n = quad*4+r, col = m = lq -> float4 along n
    for (int i = 0; i < 2; ++i) {
        int nb = n0 + wn * 32 + i * 16 + quad * 4;
        float4 bv4 = *(const float4*)&bias[nb];
        for (int j = 0; j < 4; ++j) {
            int m = m0 + wm * 64 + j * 16 + lq;
            float4 ov;
            ov.x = acc[i][j][0] + bv4.x;
            ov.y = acc[i][j][1] + bv4.y;
            ov.z = acc[i][j][2] + bv4.z;
            ov.w = acc[i][j][3] + bv4.w;
            *(float4*)&out[(size_t)m * 1024 + nb] = ov;
        }
    }
}

// ---------------- fallback GEMM (fp32 inputs, padded LDS) ----------------
template <int EPI, bool ABF16, bool WBF16>
__global__ __launch_bounds__(256) void gemm128(
    const void* __restrict__ Av, const void* __restrict__ Wv_,
    const float* __restrict__ bias, void* __restrict__ outv) {
    __shared__ __hip_bfloat16 sA[128 * LDST];
    __shared__ __hip_bfloat16 sW[128 * LDST];
    const int tid = threadIdx.x;
    const int wid = tid >> 6, lane = tid & 63;
    const int quad = lane >> 4, lq = lane & 15;
    const int wm = wid & 1, wn = wid >> 1;
    const int n0 = blockIdx.x * 128, m0 = blockIdx.y * 128;
    v4f acc[4][4] = {};
    for (int k0 = 0; k0 < 1024; k0 += 64) {
        __syncthreads();
        for (int i = 0; i < 4; ++i) {
            int f = i * 256 + tid;
            int row = f >> 3, ch = f & 7;
            if constexpr (ABF16) {
                const __hip_bfloat16* A = (const __hip_bfloat16*)Av;
                *(int4*)&sA[row * LDST + ch * 8] =
                    *(const int4*)&A[(size_t)(m0 + row) * 1024 + k0 + ch * 8];
            } else {
                const float* A = (const float*)Av;
                *(v8us*)&sA[row * LDST + ch * 8] =
                    load8_f32_to_bf16(&A[(size_t)(m0 + row) * 1024 + k0 + ch * 8]);
            }
            if constexpr (WBF16) {
                const __hip_bfloat16* W = (const __hip_bfloat16*)Wv_;
                *(int4*)&sW[row * LDST + ch * 8] =
                    *(const int4*)&W[(size_t)(n0 + row) * 1024 + k0 + ch * 8];
            } else {
                const float* W = (const float*)Wv_;
                *(v8us*)&sW[row * LDST + ch * 8] =
                    load8_f32_to_bf16(&W[(size_t)(n0 + row) * 1024 + k0 + ch * 8]);
            }
        }
        __syncthreads();
        for (int c = 0; c < 2; ++c) {
            v8bf af[4], wf[4];
            for (int mf = 0; mf < 4; ++mf)
                af[mf] = *(const v8bf*)&sA[(wm * 64 + mf * 16 + lq) * LDST + c * 32 + quad * 8];
            for (int nf = 0; nf < 4; ++nf)
                wf[nf] = *(const v8bf*)&sW[(wn * 64 + nf * 16 + lq) * LDST + c * 32 + quad * 8];
            for (int mf = 0; mf < 4; ++mf)
                for (int nf = 0; nf < 4; ++nf)
                    acc[mf][nf] = __builtin_amdgcn_mfma_f32_16x16x32_bf16(
                        af[mf], wf[nf], acc[mf][nf], 0, 0, 0);
        }
    }
    for (int nf = 0; nf < 4; ++nf) {
        int n = n0 + wn * 64 + nf * 16 + lq;
        float bv = bias[n];
        for (int mf = 0; mf < 4; ++mf) {
            int mbase = m0 + wm * 64 + mf * 16 + quad * 4;
            if constexpr (EPI == 2) {
                __hip_bfloat16* out = (__hip_bfloat16*)outv;
                int bb = mbase >> 11, t0 = mbase & 2047;
                int hh = n >> 6, dd = n & 63;
                ushort4 pk;
                pk.x = f2bfbits(acc[mf][nf][0] + bv);
                pk.y = f2bfbits(acc[mf][nf][1] + bv);
                pk.z = f2bfbits(acc[mf][nf][2] + bv);
                pk.w = f2bfbits(acc[mf][nf][3] + bv);
                *(ushort4*)&out[(((size_t)(bb * H_ + hh)) * HD_ + dd) * T_ + t0] = pk;
            } else {
                for (int r = 0; r < 4; ++r) {
                    int m = mbase + r;
                    float v = acc[mf][nf][r] + bv;
                    if constexpr (EPI == 0) {
                        __hip_bfloat16* out = (__hip_bfloat16*)outv;
                        v *= 0.125f * LOG2E;
                        int bb = m >> 11, t = m & 2047, hh = n >> 6, dd = n & 63;
                        out[(((size_t)(bb * H_ + hh)) * T_ + t) * HD_ + dd] = __float2bfloat16(v);
                    } else if constexpr (EPI == 1) {
                        __hip_bfloat16* out = (__hip_bfloat16*)outv;
                        int bb = m >> 11, t = m & 2047, hh = n >> 6, dd = n & 63;
                        out[(((size_t)(bb * H_ + hh)) * T_ + t) * HD_ + dd] = __float2bfloat16(v);
                    } else {
                        float* out = (float*)outv;
                        out[(size_t)m * 1024 + n] = v;
                    }
                }
            }
        }
    }
}

// -------- flash attention: 512 threads, 8 waves x 16 q rows (R8) ---------
// grid (T/128, B*H). S^T = K Q^T in exp2 domain (q carries 0.125*log2e).
// Single-buffer 64-key K/V staging, 2-barrier loop; mask prefetched before
// the barriers. Ping-pong dbuf tried twice (R7/R9): regressed both times —
// implicit 16-waves/CU overlap already covers the drain (m99/m100 analog).
__global__ __launch_bounds__(512) void attn_kernel(
    const __hip_bfloat16* __restrict__ q, const __hip_bfloat16* __restrict__ k,
    const __hip_bfloat16* __restrict__ vt, const float* __restrict__ mask,
    __hip_bfloat16* __restrict__ out) {
    __shared__ __hip_bfloat16 sK[64 * 64];       // [key][d], swizzled
    __shared__ __hip_bfloat16 sV[64 * 64];       // [d][key], swizzled
    __shared__ __hip_bfloat16 pT[8][16 * PSTR];  // per-wave P^T [q][64key]
    const int tid = threadIdx.x;
    const int wid = tid >> 6, lane = tid & 63;
    const int quad = lane >> 4, lq = lane & 15;
    const int bh = blockIdx.y;
    const int b = bh >> 4, h = bh & 15;
    const int qt = blockIdx.x * 128 + wid * 16 + lq;  // this lane's q row

    v8bf bq[2];
    for (int c = 0; c < 2; ++c)
        bq[c] = *(const v8bf*)&q[((size_t)bh * T_ + qt) * HD_ + c * 32 + quad * 8];

    const float* mrow = mask + ((size_t)b * T_ + qt) * T_;
    const __hip_bfloat16* kbase = k + (size_t)bh * T_ * HD_;
    const __hip_bfloat16* vbase = vt + (size_t)bh * HD_ * T_;

    const int srow = tid >> 3, spos = tid & 7;
    const int sswz = (spos ^ (srow & 7)) * 8;

    float l = 0.f;
    v4f o[4] = {};

    for (int kt0 = 0; kt0 < T_; kt0 += 64) {
        float4 mg[4];
        for (int ki = 0; ki < 4; ++ki)
            mg[ki] = *(const float4*)&mrow[kt0 + ki * 16 + quad * 4];

        __syncthreads();  // prev tile's sK/sV reads complete
        async16(&kbase[(size_t)(kt0 + srow) * HD_ + sswz], &sK[tid * 8]);
        async16(&vbase[(size_t)srow * T_ + kt0 + sswz], &sV[tid * 8]);
        __syncthreads();  // staging complete (vmcnt(0) drain)

        v4f st[4] = {};
        for (int ki = 0; ki < 4; ++ki)
            for (int c = 0; c < 2; ++c) {
                int row = ki * 16 + lq;
                v8bf ka = *(const v8bf*)&sK[row * 64 + (((c * 4 + quad) ^ (lq & 7)) * 8)];
                st[ki] = __builtin_amdgcn_mfma_f32_16x16x32_bf16(ka, bq[c], st[ki], 0, 0, 0);
            }
        for (int ki = 0; ki < 4; ++ki)
            for (int r = 0; r < 4; ++r) {
                st[ki][r] = __builtin_amdgcn_exp2f(fmaf((&mg[ki].x)[r], LOG2E, st[ki][r]));
                l += st[ki][r];
            }
        for (int ki = 0; ki < 4; ++ki) {
            ushort4 pk;
            pk.x = f2bfbits(st[ki][0]); pk.y = f2bfbits(st[ki][1]);
            pk.z = f2bfbits(st[ki][2]); pk.w = f2bfbits(st[ki][3]);
            *(ushort4*)&pT[wid][lq * PSTR + ki * 16 + quad * 4] = pk;
        }
        for (int c = 0; c < 2; ++c) {
            v8bf pb = *(const v8bf*)&pT[wid][lq * PSTR + c * 32 + quad * 8];
            for (int nt = 0; nt < 4; ++nt) {
                int row = nt * 16 + lq;
                v8bf va = *(const v8bf*)&sV[row * 64 + (((c * 4 + quad) ^ (lq & 7)) * 8)];
                o[nt] = __builtin_amdgcn_mfma_f32_16x16x32_bf16(va, pb, o[nt], 0, 0, 0);
            }
        }
    }

    l += __shfl_xor(l, 16);
    l += __shfl_xor(l, 32);
    float inv = 1.0f / l;
    for (int nt = 0; nt < 4; ++nt) {
        ushort4 pk;
        pk.x = f2bfbits(o[nt][0] * inv); pk.y = f2bfbits(o[nt][1] * inv);
        pk.z = f2bfbits(o[nt][2] * inv); pk.w = f2bfbits(o[nt][3] * inv);
        *(ushort4*)&out[((size_t)b * T_ + qt) * D_ + h * HD_ + nt * 16 + quad * 4] = pk;
    }
}

extern "C" void kernel_launch(void* const* d_in, const int* in_sizes, int n_in,
                              void* d_out, int out_size, void* d_ws, size_t ws_size,
                              hipStream_t stream) {
    const float* hs   = (const float*)d_in[0];
    const float* mask = (const float*)d_in[1];
    const float* Wq   = (const float*)d_in[2];
    const float* bq   = (const float*)d_in[3];
    const float* Wk   = (const float*)d_in[4];
    const float* bk   = (const float*)d_in[5];
    const float* Wv   = (const float*)d_in[6];
    const float* bv   = (const float*)d_in[7];
    const float* Wo   = (const float*)d_in[8];
    const float* bo   = (const float*)d_in[9];
    float* out = (float*)d_out;

    const size_t TEN = (size_t)B_ * H_ * T_ * HD_;  // 4,194,304
    const size_t WEL = (size_t)D_ * D_;             // 1,048,576
    __hip_bfloat16* q_ws  = (__hip_bfloat16*)d_ws;
    __hip_bfloat16* k_ws  = q_ws + TEN;
    __hip_bfloat16* vt_ws = k_ws + TEN;
    __hip_bfloat16* at_ws = vt_ws + TEN;

    dim3 qkvgrid(3072 / 128, M_ / 128);  // (24, 32) = 768 blocks -> 3/CU
    dim3 outgrid(D_ / 64, M_ / 128);     // (16, 32) = 512 blocks
    dim3 ogrid(D_ / 128, M_ / 128);      // fallback grid
    dim3 agrid(T_ / 128, B_ * H_);       // (16, 32) = 512 blocks of 512 thr

    const size_t need = (4 * TEN + TEN + 4 * WEL) * sizeof(__hip_bfloat16);
    if (ws_size >= need) {
        __hip_bfloat16* hsb = at_ws + TEN;
        __hip_bfloat16* wqb = hsb + TEN;   // wqb/wkb/wvb contiguous = [3072,1024]
        __hip_bfloat16* wkb = wqb + WEL;
        __hip_bfloat16* wvb = wkb + WEL;
        __hip_bfloat16* wob = wvb + WEL;
        cvt_multi<<<2048 + 4 * 512, 256, 0, stream>>>(hs, Wq, Wk, Wv, Wo,
                                                      hsb, wqb, wkb, wvb, wob);
        gemm_qkv<<<qkvgrid, 256, 0, stream>>>(hsb, wqb, bq, bk, bv, q_ws, k_ws, vt_ws);
        attn_kernel<<<agrid, 512, 0, stream>>>(q_ws, k_ws, vt_ws, mask, at_ws);
        gemm_out<<<outgrid, 256, 0, stream>>>(at_ws, wob, bo, out);
    } else {
        gemm128<0, false, false><<<ogrid, 256, 0, stream>>>(hs, Wq, bq, q_ws);
        gemm128<1, false, false><<<ogrid, 256, 0, stream>>>(hs, Wk, bk, k_ws);
        gemm128<2, false, false><<<ogrid, 256, 0, stream>>>(hs, Wv, bv, vt_ws);
        attn_kernel<<<agrid, 512, 0, stream>>>(q_ws, k_ws, vt_ws, mask, at_ws);
        gemm128<3, true, false><<<ogrid, 256, 0, stream>>>(at_ws, Wo, bo, out);
    }
}